// Round 6
// baseline (368.382 us; speedup 1.0000x reference)
//
#include <hip/hip_runtime.h>
#include <hip/hip_bf16.h>
#include <math.h>

typedef __attribute__((ext_vector_type(8))) short short8;
typedef __attribute__((ext_vector_type(4))) float f32x4;

#define VOCAB 8192
#define NSAMP 8192
#define INTER 4352
#define EMB   512

// ---- workspace layout (bytes) ----
#define OFF_CNT    0            // 8192*4   = 32768
#define OFF_A1     32768        // 4352*4   = 17408
#define OFF_M1     50176        // 17408
#define OFF_A2     67584        // 2048
#define OFF_M2     69632        // 2048
#define OFF_PS1B   71680        // [512][128] f32 = 262144 (region reserved ~1 MB)
#define OFF_DONE   333824       // 1 u32 (inside reserved gap)
#define OFF_PS2B   1120256      // [512][128] f32 = 262144
#define OFF_W2B    2168832      // 512*4352*2 = 4456448
#define OFF_HACT   6625280      // 8192*4352*2 = 71303168
#define OFF_H2     77928448     // 8192*512*4 = 16777216

__device__ __forceinline__ float gelu_exact(float x) {
    return 0.5f * x * (1.0f + erff(x * 0.70710678118654752f));
}
__device__ __forceinline__ unsigned short f2bf(float x) {
    __hip_bfloat16 b = __float2bfloat16(x);
    return *reinterpret_cast<unsigned short*>(&b);
}
__device__ __forceinline__ void async16(const unsigned short* g, unsigned short* l) {
    __builtin_amdgcn_global_load_lds(
        (const __attribute__((address_space(1))) void*)g,
        (__attribute__((address_space(3))) void*)l, 16, 0, 0);
}

// ------- fused zero+hist: one block, LDS histogram -------
__global__ __launch_bounds__(1024) void k_hist1b(const int* __restrict__ xt,
                                                 int* __restrict__ cnt,
                                                 unsigned* __restrict__ done) {
    __shared__ int h[VOCAB];
    const int t = threadIdx.x;
    #pragma unroll
    for (int i = 0; i < 8; ++i) h[t + i * 1024] = 0;
    if (t == 0) *done = 0u;
    __syncthreads();
    const int4* x4 = (const int4*)xt;
    int4 a = x4[t], b = x4[t + 1024];
    atomicAdd(&h[a.x], 1); atomicAdd(&h[a.y], 1);
    atomicAdd(&h[a.z], 1); atomicAdd(&h[a.w], 1);
    atomicAdd(&h[b.x], 1); atomicAdd(&h[b.y], 1);
    atomicAdd(&h[b.z], 1); atomicAdd(&h[b.w], 1);
    __syncthreads();
    #pragma unroll
    for (int i = 0; i < 2; ++i)
        ((int4*)cnt)[t + i * 1024] = ((const int4*)h)[t + i * 1024];
}

// ---------------- BN1 stats: one wave per channel row, fused finalize ------------
__global__ __launch_bounds__(256) void k_stats1(const float* __restrict__ W1,
                                                const int* __restrict__ cnt,
                                                const float* __restrict__ g1,
                                                float* __restrict__ a1,
                                                float* __restrict__ m1) {
    const int t = threadIdx.x, lane = t & 63, w = t >> 6;
    const int row = blockIdx.x * 4 + w;
    const float* wr = W1 + (size_t)row * VOCAB;
    float s1 = 0.f, s2 = 0.f;
    #pragma unroll 8
    for (int it = 0; it < 32; ++it) {
        int v = it * 256 + lane * 4;
        float4 x = *(const float4*)(wr + v);
        int4 c = *(const int4*)(cnt + v);
        float cx = (float)c.x, cy = (float)c.y, cz = (float)c.z, cw = (float)c.w;
        s1 += cx * x.x + cy * x.y + cz * x.z + cw * x.w;
        s2 += cx * x.x * x.x + cy * x.y * x.y + cz * x.z * x.z + cw * x.w * x.w;
    }
    #pragma unroll
    for (int d = 1; d < 64; d <<= 1) {
        s1 += __shfl_xor(s1, d);
        s2 += __shfl_xor(s2, d);
    }
    if (lane == 0) {
        float m = s1 * (1.f / NSAMP);
        float var = s2 * (1.f / NSAMP) - m * m;
        a1[row] = g1[row] * rsqrtf(var + 1e-5f);
        m1[row] = m;
    }
}

// --- fused: build Hact (blocks 0..2175) + W2 fp32->bf16 (blocks 2176..4351) ---
__global__ __launch_bounds__(256) void k_buildw2(const float* __restrict__ W1,
                                                 const float* __restrict__ a1,
                                                 const float* __restrict__ m1,
                                                 const float* __restrict__ beta1,
                                                 unsigned short* __restrict__ Hact,
                                                 const float* __restrict__ W2,
                                                 unsigned short* __restrict__ W2b) {
    const int bx = blockIdx.x;
    const int t = threadIdx.x;
    if (bx >= 2176) {   // W2 conversion part
        int idx = ((bx - 2176) * 256 + t) * 4;
        float4 w = *(const float4*)(W2 + idx);
        ushort4 u;
        u.x = f2bf(w.x); u.y = f2bf(w.y); u.z = f2bf(w.z); u.w = f2bf(w.w);
        *(ushort4*)(W2b + idx) = u;
        return;
    }
    const int i0 = (bx % 68) * 64;
    const int v0 = (bx / 68) * 256;
    const int c0 = (t & 15) * 4;
    const int vg = (t >> 4) * 4;   // 0..60
    float4 av = *(const float4*)(a1 + i0 + c0);
    float4 mv = *(const float4*)(m1 + i0 + c0);
    float4 bv = *(const float4*)(beta1 + i0 + c0);
    const float* ap = (const float*)&av;
    const float* mp = (const float*)&mv;
    const float* bp = (const float*)&bv;
    #pragma unroll
    for (int vi = 0; vi < 4; ++vi) {
        int vb = v0 + vi * 64 + vg;
        float wf[4][4];
        #pragma unroll
        for (int j = 0; j < 4; ++j)
            *(float4*)&wf[j][0] = *(const float4*)(W1 + (size_t)(i0 + c0 + j) * VOCAB + vb);
        #pragma unroll
        for (int k = 0; k < 4; ++k) {
            ushort4 o;
            o.x = f2bf(gelu_exact(ap[0] * (wf[0][k] - mp[0]) + bp[0]));
            o.y = f2bf(gelu_exact(ap[1] * (wf[1][k] - mp[1]) + bp[1]));
            o.z = f2bf(gelu_exact(ap[2] * (wf[2][k] - mp[2]) + bp[2]));
            o.w = f2bf(gelu_exact(ap[3] * (wf[3][k] - mp[3]) + bp[3]));
            *(ushort4*)&Hact[(size_t)(vb + k) * INTER + i0 + c0] = o;
        }
    }
}

// ------- full-K GEMM: h2 = Hact[8192,4352] * W2b[512,4352]^T (bf16 MFMA) ---------
// ROUND 6 RESTRUCTURE: 256-thread blocks (4 waves, 2x2, wave tile 64Mx32N),
// tile 128M x 64N, grid 512 (2 work-blocks/CU), LDS 48 KB -> 3 blocks/CU
// co-resident. Round-4/5 PMC showed OccupancyPercent 16.7% (= 2/3 of the 25%
// single-block ceiling): grid==CU-count with one 8-wave barrier-locked block/CU
// left no backfill for stragglers and no independent waves to overlap pipes.
// Multi-block co-residency restores the m97-style implicit wave-level overlap.
// Simple 2-phase double-buffer (counted-vmcnt + stagger measured neutral).
// XCD colocation kept: mblk = bid&63 -> A-stripe's 8 blocks all on XCD bid%8.
// Epilogue: h2 store + cnt-weighted BN2 partials; last block finalizes a2/m2.
__global__ __launch_bounds__(256) void k_gemm(const unsigned short* __restrict__ A,
                                              const unsigned short* __restrict__ B,
                                              const int* __restrict__ cnt,
                                              float* __restrict__ h2,
                                              float* __restrict__ ps1,
                                              float* __restrict__ ps2,
                                              const float* __restrict__ g2,
                                              float* __restrict__ a2,
                                              float* __restrict__ m2,
                                              unsigned* __restrict__ done) {
    __shared__ __align__(16) unsigned short sA[2][128 * 64];
    __shared__ __align__(16) unsigned short sB[2][64 * 64];
    const int bid = blockIdx.x;
    const int mblk = bid & 63;      // same mblk -> same XCD (bid mod 8 equal)
    const int nblk = bid >> 6;      // 0..7
    const int m0 = mblk * 128;
    const int n0 = nblk * 64;
    const int t = threadIdx.x;
    const int lane = t & 63;
    const int wave = t >> 6;                     // 0..3
    const int wr = wave >> 1, wc = wave & 1;     // 2x2 waves, each 64M x 32N
    const int mq = lane & 15, kq = lane >> 4;
    const int srow = lane >> 3;                  // staging row within 8-row group
    const int sgrp = lane & 7;                   // staging 16B-group
    const int scol = (sgrp ^ srow) * 8;          // swizzled global column (shorts)
    const int swz = mq & 7;                      // fragment-read swizzle

    const unsigned short* Ab = A + (size_t)(m0 + wave * 32 + srow) * INTER + scol;
    const unsigned short* Bb = B + (size_t)(n0 + wave * 16 + srow) * INTER + scol;

    f32x4 acc[4][2];
    #pragma unroll
    for (int r = 0; r < 4; ++r)
        #pragma unroll
        for (int c = 0; c < 2; ++c) acc[r][c] = (f32x4){0.f, 0.f, 0.f, 0.f};

    auto stage = [&](int buf, int tile) {
        const int k0 = tile * 64;
        #pragma unroll
        for (int p = 0; p < 4; ++p)     // A: 128 rows, wave stages rows wave*32+p*8
            async16(Ab + (size_t)(p * 8) * INTER + k0, &sA[buf][(wave * 32 + p * 8) * 64]);
        #pragma unroll
        for (int p = 0; p < 2; ++p)     // B: 64 rows, wave stages rows wave*16+p*8
            async16(Bb + (size_t)(p * 8) * INTER + k0, &sB[buf][(wave * 16 + p * 8) * 64]);
    };
    auto compute = [&](int buf) {
        #pragma unroll
        for (int kk = 0; kk < 64; kk += 32) {
            const int gbase = kq + (kk >> 3);
            short8 af[4], bfr[2];
            #pragma unroll
            for (int r = 0; r < 4; ++r)
                af[r] = *(const short8*)&sA[buf][(wr * 64 + r * 16 + mq) * 64 + ((gbase ^ swz) * 8)];
            #pragma unroll
            for (int c = 0; c < 2; ++c)
                bfr[c] = *(const short8*)&sB[buf][(wc * 32 + c * 16 + mq) * 64 + ((gbase ^ swz) * 8)];
            __builtin_amdgcn_s_setprio(1);
            #pragma unroll
            for (int r = 0; r < 4; ++r)
                #pragma unroll
                for (int c = 0; c < 2; ++c)
                    acc[r][c] = __builtin_amdgcn_mfma_f32_16x16x32_bf16(af[r], bfr[c], acc[r][c], 0, 0, 0);
            __builtin_amdgcn_s_setprio(0);
        }
    };

    stage(0, 0);
    __syncthreads();
    #pragma unroll 1
    for (int ti = 0; ti < 67; ++ti) {
        stage((ti + 1) & 1, ti + 1);    // next tile's loads fly under compute
        compute(ti & 1);
        __syncthreads();                // drains vmcnt: next buf ready, cur buf free
    }
    compute(1);                          // tile 67

    // ---- epilogue: h2 store + fused cnt-weighted BN2 partial stats ----
    float s1[2] = {0.f, 0.f}, s2[2] = {0.f, 0.f};
    #pragma unroll
    for (int r = 0; r < 4; ++r) {
        const int rowb = m0 + wr * 64 + r * 16 + kq * 4;
        int4 cw = *(const int4*)(cnt + rowb);
        float w0 = (float)cw.x, w1 = (float)cw.y, w2 = (float)cw.z, w3 = (float)cw.w;
        #pragma unroll
        for (int c = 0; c < 2; ++c) {
            const int col = n0 + wc * 32 + c * 16 + mq;
            float v0 = acc[r][c][0], v1 = acc[r][c][1], v2 = acc[r][c][2], v3 = acc[r][c][3];
            h2[(size_t)(rowb + 0) * EMB + col] = v0;
            h2[(size_t)(rowb + 1) * EMB + col] = v1;
            h2[(size_t)(rowb + 2) * EMB + col] = v2;
            h2[(size_t)(rowb + 3) * EMB + col] = v3;
            s1[c] += w0 * v0 + w1 * v1 + w2 * v2 + w3 * v3;
            s2[c] += w0 * v0 * v0 + w1 * v1 * v1 + w2 * v2 * v2 + w3 * v3 * v3;
        }
    }
    #pragma unroll
    for (int c = 0; c < 2; ++c) {
        s1[c] += __shfl_xor(s1[c], 16);
        s2[c] += __shfl_xor(s2[c], 16);
        s1[c] += __shfl_xor(s1[c], 32);
        s2[c] += __shfl_xor(s2[c], 32);
    }
    if (lane < 16) {
        const int slot = mblk * 2 + wr;          // 64 mblk x 2 wr = 128 slots
        #pragma unroll
        for (int c = 0; c < 2; ++c) {
            const int col = n0 + wc * 32 + c * 16 + mq;
            ps1[(size_t)col * 128 + slot] = s1[c];
            ps2[(size_t)col * 128 + slot] = s2[c];
        }
    }

    // ---- last-block finalize of BN2 stats ----
    __shared__ bool sLast;
    __syncthreads();
    if (t == 0) {
        __threadfence();
        sLast = (atomicAdd(done, 1u) == 511u);
    }
    __syncthreads();
    if (sLast) {
        __threadfence();
        #pragma unroll
        for (int e = t; e < 512; e += 256) {
            float f1 = 0.f, f2 = 0.f;
            const float4* p1 = (const float4*)(ps1 + (size_t)e * 128);
            const float4* p2 = (const float4*)(ps2 + (size_t)e * 128);
            #pragma unroll 8
            for (int i = 0; i < 32; ++i) {
                float4 u = p1[i]; f1 += u.x + u.y + u.z + u.w;
                float4 v = p2[i]; f2 += v.x + v.y + v.z + v.w;
            }
            float m = f1 * (1.f / NSAMP);
            float var = f2 * (1.f / NSAMP) - m * m;
            a2[e] = g2[e] * rsqrtf(var + 1e-5f);
            m2[e] = m;
        }
    }
}

// ---------------- final gather + BN2 + gelu ----------------
__global__ __launch_bounds__(256) void k_final(const float* __restrict__ h2,
                                               const int* __restrict__ xt,
                                               const float* __restrict__ a2,
                                               const float* __restrict__ m2,
                                               const float* __restrict__ beta2,
                                               float* __restrict__ out) {
    const int t = threadIdx.x;
    const int n = blockIdx.x * 2 + (t >> 7);
    const int e = (t & 127) * 4;
    const int v = xt[n];
    float4 h = *(const float4*)(h2 + (size_t)v * EMB + e);
    float4 a = *(const float4*)(a2 + e);
    float4 m = *(const float4*)(m2 + e);
    float4 b = *(const float4*)(beta2 + e);
    float4 o;
    o.x = gelu_exact(a.x * (h.x - m.x) + b.x);
    o.y = gelu_exact(a.y * (h.y - m.y) + b.y);
    o.z = gelu_exact(a.z * (h.z - m.z) + b.z);
    o.w = gelu_exact(a.w * (h.w - m.w) + b.w);
    *(float4*)(out + (size_t)n * EMB + e) = o;
}

extern "C" void kernel_launch(void* const* d_in, const int* in_sizes, int n_in,
                              void* d_out, int out_size, void* d_ws, size_t ws_size,
                              hipStream_t stream) {
    const int* xt      = (const int*)d_in[0];
    const float* W1    = (const float*)d_in[1];
    // d_in[2] = b1 (cancels in BN), d_in[6] = b2 (cancels in BN)
    const float* g1    = (const float*)d_in[3];
    const float* beta1 = (const float*)d_in[4];
    const float* W2    = (const float*)d_in[5];
    const float* g2    = (const float*)d_in[7];
    const float* beta2 = (const float*)d_in[8];
    float* out = (float*)d_out;

    char* ws = (char*)d_ws;
    int*   cnt  = (int*)  (ws + OFF_CNT);
    float* a1   = (float*)(ws + OFF_A1);
    float* m1   = (float*)(ws + OFF_M1);
    float* a2   = (float*)(ws + OFF_A2);
    float* m2   = (float*)(ws + OFF_M2);
    float* ps1b = (float*)(ws + OFF_PS1B);
    float* ps2b = (float*)(ws + OFF_PS2B);
    unsigned* done = (unsigned*)(ws + OFF_DONE);
    unsigned short* W2b  = (unsigned short*)(ws + OFF_W2B);
    unsigned short* Hact = (unsigned short*)(ws + OFF_HACT);
    float* h2   = (float*)(ws + OFF_H2);

    k_hist1b<<<1, 1024, 0, stream>>>(xt, cnt, done);
    k_stats1<<<1088, 256, 0, stream>>>(W1, cnt, g1, a1, m1);
    k_buildw2<<<4352, 256, 0, stream>>>(W1, a1, m1, beta1, Hact, W2, W2b);
    k_gemm<<<512, 256, 0, stream>>>(Hact, W2b, cnt, h2, ps1b, ps2b, g2, a2, m2, done);
    k_final<<<4096, 256, 0, stream>>>(h2, xt, a2, m2, beta2, out);
}

// Round 8
// 322.906 us; speedup vs baseline: 1.1408x; 1.1408x over previous
//
#include <hip/hip_runtime.h>
#include <hip/hip_bf16.h>
#include <math.h>

typedef __attribute__((ext_vector_type(8))) short short8;
typedef __attribute__((ext_vector_type(4))) float f32x4;

#define VOCAB 8192
#define NSAMP 8192
#define INTER 4352
#define EMB   512

// ---- workspace layout (bytes) ----
#define OFF_CNT    0            // 8192*4   = 32768
#define OFF_A1     32768        // 4352*4   = 17408
#define OFF_M1     50176        // 17408
#define OFF_A2     67584        // 2048
#define OFF_M2     69632        // 2048
#define OFF_PS1B   71680        // [512][512] f32 = 1048576
#define OFF_PS2B   1120256      // [512][512] f32 = 1048576
#define OFF_W2B    2168832      // 512*4352*2 = 4456448
#define OFF_HACT   6625280      // 8192*4352*2 = 71303168
#define OFF_H2     77928448     // hpart chunk 0 (= final h2), 8192*512*4 = 16777216
#define PART_BYTES 16777216ULL  // chunk 1 at OFF_H2 + PART_BYTES

__device__ __forceinline__ float gelu_exact(float x) {
    return 0.5f * x * (1.0f + erff(x * 0.70710678118654752f));
}
__device__ __forceinline__ unsigned short f2bf(float x) {
    __hip_bfloat16 b = __float2bfloat16(x);
    return *reinterpret_cast<unsigned short*>(&b);
}
__device__ __forceinline__ void async16(const unsigned short* g, unsigned short* l) {
    __builtin_amdgcn_global_load_lds(
        (const __attribute__((address_space(1))) void*)g,
        (__attribute__((address_space(3))) void*)l, 16, 0, 0);
}

// ------- fused zero+hist: one block, LDS histogram -------
__global__ __launch_bounds__(1024) void k_hist1b(const int* __restrict__ xt,
                                                 int* __restrict__ cnt) {
    __shared__ int h[VOCAB];
    const int t = threadIdx.x;
    #pragma unroll
    for (int i = 0; i < 8; ++i) h[t + i * 1024] = 0;
    __syncthreads();
    const int4* x4 = (const int4*)xt;
    int4 a = x4[t], b = x4[t + 1024];
    atomicAdd(&h[a.x], 1); atomicAdd(&h[a.y], 1);
    atomicAdd(&h[a.z], 1); atomicAdd(&h[a.w], 1);
    atomicAdd(&h[b.x], 1); atomicAdd(&h[b.y], 1);
    atomicAdd(&h[b.z], 1); atomicAdd(&h[b.w], 1);
    __syncthreads();
    #pragma unroll
    for (int i = 0; i < 2; ++i)
        ((int4*)cnt)[t + i * 1024] = ((const int4*)h)[t + i * 1024];
}

// ---------------- BN1 stats: one wave per channel row, fused finalize ------------
__global__ __launch_bounds__(256) void k_stats1(const float* __restrict__ W1,
                                                const int* __restrict__ cnt,
                                                const float* __restrict__ g1,
                                                float* __restrict__ a1,
                                                float* __restrict__ m1) {
    const int t = threadIdx.x, lane = t & 63, w = t >> 6;
    const int row = blockIdx.x * 4 + w;
    const float* wr = W1 + (size_t)row * VOCAB;
    float s1 = 0.f, s2 = 0.f;
    #pragma unroll 8
    for (int it = 0; it < 32; ++it) {
        int v = it * 256 + lane * 4;
        float4 x = *(const float4*)(wr + v);
        int4 c = *(const int4*)(cnt + v);
        float cx = (float)c.x, cy = (float)c.y, cz = (float)c.z, cw = (float)c.w;
        s1 += cx * x.x + cy * x.y + cz * x.z + cw * x.w;
        s2 += cx * x.x * x.x + cy * x.y * x.y + cz * x.z * x.z + cw * x.w * x.w;
    }
    #pragma unroll
    for (int d = 1; d < 64; d <<= 1) {
        s1 += __shfl_xor(s1, d);
        s2 += __shfl_xor(s2, d);
    }
    if (lane == 0) {
        float m = s1 * (1.f / NSAMP);
        float var = s2 * (1.f / NSAMP) - m * m;
        a1[row] = g1[row] * rsqrtf(var + 1e-5f);
        m1[row] = m;
    }
}

// --- fused: build Hact (blocks 0..2175) + W2 fp32->bf16 (blocks 2176..4351) ---
__global__ __launch_bounds__(256) void k_buildw2(const float* __restrict__ W1,
                                                 const float* __restrict__ a1,
                                                 const float* __restrict__ m1,
                                                 const float* __restrict__ beta1,
                                                 unsigned short* __restrict__ Hact,
                                                 const float* __restrict__ W2,
                                                 unsigned short* __restrict__ W2b) {
    const int bx = blockIdx.x;
    const int t = threadIdx.x;
    if (bx >= 2176) {   // W2 conversion part
        int idx = ((bx - 2176) * 256 + t) * 4;
        float4 w = *(const float4*)(W2 + idx);
        ushort4 u;
        u.x = f2bf(w.x); u.y = f2bf(w.y); u.z = f2bf(w.z); u.w = f2bf(w.w);
        *(ushort4*)(W2b + idx) = u;
        return;
    }
    const int i0 = (bx % 68) * 64;
    const int v0 = (bx / 68) * 256;
    const int c0 = (t & 15) * 4;
    const int vg = (t >> 4) * 4;   // 0..60
    float4 av = *(const float4*)(a1 + i0 + c0);
    float4 mv = *(const float4*)(m1 + i0 + c0);
    float4 bv = *(const float4*)(beta1 + i0 + c0);
    const float* ap = (const float*)&av;
    const float* mp = (const float*)&mv;
    const float* bp = (const float*)&bv;
    #pragma unroll
    for (int vi = 0; vi < 4; ++vi) {
        int vb = v0 + vi * 64 + vg;
        float wf[4][4];
        #pragma unroll
        for (int j = 0; j < 4; ++j)
            *(float4*)&wf[j][0] = *(const float4*)(W1 + (size_t)(i0 + c0 + j) * VOCAB + vb);
        #pragma unroll
        for (int k = 0; k < 4; ++k) {
            ushort4 o;
            o.x = f2bf(gelu_exact(ap[0] * (wf[0][k] - mp[0]) + bp[0]));
            o.y = f2bf(gelu_exact(ap[1] * (wf[1][k] - mp[1]) + bp[1]));
            o.z = f2bf(gelu_exact(ap[2] * (wf[2][k] - mp[2]) + bp[2]));
            o.w = f2bf(gelu_exact(ap[3] * (wf[3][k] - mp[3]) + bp[3]));
            *(ushort4*)&Hact[(size_t)(vb + k) * INTER + i0 + c0] = o;
        }
    }
}

// ------- split-K GEMM: hpart[ks] = Hact[8192,Kslice] * W2b[512,Kslice]^T -------
// Tile 128M x 128N, 512 thr = 8 waves (2x4, wave 64Mx32N) — the best-measured
// FLOPs/step shape (r4: 25.4 cyc/MFMA vs r6 small-tile 29.9). Grid 256*S:
// bid = ks*256 + nblk*64 + mblk. XCD colocation: the 4 nblk of one (mblk,ks)
// differ by 64 -> same bid%8 -> same XCD -> A-stripe fetched once (r4: -92MB).
// LDS 64 KB -> with S=2 TWO 8-wave blocks co-resident per CU (16 waves/CU):
// r6 proved co-residency lifts per-step throughput +69%; split-K supplies the
// second block without shrinking the tile. Simple r2-proven 2-phase loop
// (stage(next) -> compute(cur) -> __syncthreads; depth-4 vmcnt measured neutral).
__global__ __launch_bounds__(512) void k_gemm(const unsigned short* __restrict__ A,
                                              const unsigned short* __restrict__ B,
                                              float* __restrict__ hpart, int kPer) {
    __shared__ __align__(16) unsigned short sA[2][128 * 64];
    __shared__ __align__(16) unsigned short sB[2][128 * 64];
    const int bid = blockIdx.x;
    const int mblk = bid & 63;
    const int nblk = (bid >> 6) & 3;
    const int ks   = bid >> 8;
    const int m0 = mblk * 128;
    const int n0 = nblk * 128;
    const int kbeg = ks * kPer;
    const int nsteps = kPer >> 6;
    float* C = hpart + (size_t)ks * NSAMP * EMB;
    const int t = threadIdx.x;
    const int lane = t & 63;
    const int wave = t >> 6;                     // 0..7
    const int wr = wave >> 2, wc = wave & 3;     // 2x4 waves, each 64M x 32N
    const int mq = lane & 15, kq = lane >> 4;
    const int srow = lane >> 3;                  // staging row within 8-row group
    const int sgrp = lane & 7;                   // staging 16B-group
    const int scol = (sgrp ^ srow) * 8;          // swizzled global column (shorts)
    const int swz = mq & 7;                      // fragment-read swizzle

    const unsigned short* Ab = A + (size_t)(m0 + wave * 16 + srow) * INTER + kbeg + scol;
    const unsigned short* Bb = B + (size_t)(n0 + wave * 16 + srow) * INTER + kbeg + scol;

    f32x4 acc[4][2];
    #pragma unroll
    for (int r = 0; r < 4; ++r)
        #pragma unroll
        for (int c = 0; c < 2; ++c) acc[r][c] = (f32x4){0.f, 0.f, 0.f, 0.f};

    auto stage = [&](int buf, int tile) {
        const int k0 = tile * 64;
        async16(Ab + k0,                     &sA[buf][(wave * 16) * 64]);
        async16(Ab + (size_t)8 * INTER + k0, &sA[buf][(wave * 16 + 8) * 64]);
        async16(Bb + k0,                     &sB[buf][(wave * 16) * 64]);
        async16(Bb + (size_t)8 * INTER + k0, &sB[buf][(wave * 16 + 8) * 64]);
    };
    auto compute = [&](int buf) {
        #pragma unroll
        for (int kk = 0; kk < 64; kk += 32) {
            const int gbase = kq + (kk >> 3);
            short8 af[4], bfr[2];
            #pragma unroll
            for (int r = 0; r < 4; ++r)
                af[r] = *(const short8*)&sA[buf][(wr * 64 + r * 16 + mq) * 64 + ((gbase ^ swz) * 8)];
            #pragma unroll
            for (int c = 0; c < 2; ++c)
                bfr[c] = *(const short8*)&sB[buf][(wc * 32 + c * 16 + mq) * 64 + ((gbase ^ swz) * 8)];
            __builtin_amdgcn_s_setprio(1);
            #pragma unroll
            for (int r = 0; r < 4; ++r)
                #pragma unroll
                for (int c = 0; c < 2; ++c)
                    acc[r][c] = __builtin_amdgcn_mfma_f32_16x16x32_bf16(af[r], bfr[c], acc[r][c], 0, 0, 0);
            __builtin_amdgcn_s_setprio(0);
        }
    };

    stage(0, 0);
    __syncthreads();
    #pragma unroll 1
    for (int ti = 0; ti < nsteps - 1; ++ti) {
        stage((ti + 1) & 1, ti + 1);    // next tile's loads fly under compute
        compute(ti & 1);
        __syncthreads();                // drains vmcnt: next buf ready, cur buf free
    }
    compute((nsteps - 1) & 1);

    // ---- epilogue: plain C write (stats handled in k_reduce) ----
    #pragma unroll
    for (int r = 0; r < 4; ++r) {
        const int rowb = m0 + wr * 64 + r * 16 + kq * 4;
        #pragma unroll
        for (int c = 0; c < 2; ++c) {
            const int col = n0 + wc * 32 + c * 16 + mq;
            #pragma unroll
            for (int j = 0; j < 4; ++j)
                C[(size_t)(rowb + j) * EMB + col] = acc[r][c][j];
        }
    }
}

// ------- split-K sum -> h2 + cnt-weighted BN2 partial stats (r0-proven) -------
__global__ __launch_bounds__(256) void k_reduce(const float* hpart,
                                                const int* __restrict__ cnt,
                                                float* h2,
                                                float* __restrict__ ps1,
                                                float* __restrict__ ps2, int S) {
    __shared__ float4 b1[128], b2[128];
    const int v0 = blockIdx.x * 16;
    const int t = threadIdx.x;
    const int half = t >> 7;          // wave-uniform (threads 0-127 / 128-255)
    const int c4 = (t & 127) * 4;     // column (float4)
    float4 acc1 = {0.f, 0.f, 0.f, 0.f}, acc2 = {0.f, 0.f, 0.f, 0.f};
    #pragma unroll
    for (int rp = 0; rp < 8; ++rp) {
        int r = v0 + rp * 2 + half;
        int cw_i = cnt[r];
        if (cw_i > 0) {               // unused rows: no sum, no stats, never read later
            size_t off = (size_t)r * EMB + c4;
            float4 h = *(const float4*)(hpart + off);
            for (int s = 1; s < S; ++s) {
                float4 hs = *(const float4*)(hpart + (size_t)s * NSAMP * EMB + off);
                h.x += hs.x; h.y += hs.y; h.z += hs.z; h.w += hs.w;
            }
            *(float4*)(h2 + off) = h;   // h2 aliases hpart chunk 0 (same thread r/w)
            float w = (float)cw_i;
            acc1.x += w * h.x; acc1.y += w * h.y; acc1.z += w * h.z; acc1.w += w * h.w;
            acc2.x += w * h.x * h.x; acc2.y += w * h.y * h.y;
            acc2.z += w * h.z * h.z; acc2.w += w * h.w * h.w;
        }
    }
    if (half == 1) { b1[t & 127] = acc1; b2[t & 127] = acc2; }
    __syncthreads();
    if (half == 0) {
        float4 o1 = b1[t & 127], o2 = b2[t & 127];
        o1.x += acc1.x; o1.y += acc1.y; o1.z += acc1.z; o1.w += acc1.w;
        o2.x += acc2.x; o2.y += acc2.y; o2.z += acc2.z; o2.w += acc2.w;
        ps1[(size_t)(c4 + 0) * 512 + blockIdx.x] = o1.x;
        ps1[(size_t)(c4 + 1) * 512 + blockIdx.x] = o1.y;
        ps1[(size_t)(c4 + 2) * 512 + blockIdx.x] = o1.z;
        ps1[(size_t)(c4 + 3) * 512 + blockIdx.x] = o1.w;
        ps2[(size_t)(c4 + 0) * 512 + blockIdx.x] = o2.x;
        ps2[(size_t)(c4 + 1) * 512 + blockIdx.x] = o2.y;
        ps2[(size_t)(c4 + 2) * 512 + blockIdx.x] = o2.z;
        ps2[(size_t)(c4 + 3) * 512 + blockIdx.x] = o2.w;
    }
}

// one wave per channel e: coalesced 64-lane reads over 512 block-partials
__global__ __launch_bounds__(256) void k_stats2f(const float* __restrict__ ps1,
                                                 const float* __restrict__ ps2,
                                                 const float* __restrict__ g2,
                                                 float* __restrict__ a2,
                                                 float* __restrict__ m2) {
    const int lane = threadIdx.x & 63;
    const int e = blockIdx.x * 4 + (threadIdx.x >> 6);   // 128 blocks
    float s1 = 0.f, s2 = 0.f;
    #pragma unroll
    for (int k = 0; k < 8; ++k) {
        s1 += ps1[(size_t)e * 512 + k * 64 + lane];
        s2 += ps2[(size_t)e * 512 + k * 64 + lane];
    }
    #pragma unroll
    for (int d = 1; d < 64; d <<= 1) {
        s1 += __shfl_xor(s1, d);
        s2 += __shfl_xor(s2, d);
    }
    if (lane == 0) {
        float m = s1 * (1.f / NSAMP);
        float var = s2 * (1.f / NSAMP) - m * m;
        a2[e] = g2[e] * rsqrtf(var + 1e-5f);
        m2[e] = m;
    }
}

// ---------------- final gather + BN2 + gelu ----------------
__global__ __launch_bounds__(256) void k_final(const float* __restrict__ h2,
                                               const int* __restrict__ xt,
                                               const float* __restrict__ a2,
                                               const float* __restrict__ m2,
                                               const float* __restrict__ beta2,
                                               float* __restrict__ out) {
    const int t = threadIdx.x;
    const int n = blockIdx.x * 2 + (t >> 7);
    const int e = (t & 127) * 4;
    const int v = xt[n];
    float4 h = *(const float4*)(h2 + (size_t)v * EMB + e);
    float4 a = *(const float4*)(a2 + e);
    float4 m = *(const float4*)(m2 + e);
    float4 b = *(const float4*)(beta2 + e);
    float4 o;
    o.x = gelu_exact(a.x * (h.x - m.x) + b.x);
    o.y = gelu_exact(a.y * (h.y - m.y) + b.y);
    o.z = gelu_exact(a.z * (h.z - m.z) + b.z);
    o.w = gelu_exact(a.w * (h.w - m.w) + b.w);
    *(float4*)(out + (size_t)n * EMB + e) = o;
}

extern "C" void kernel_launch(void* const* d_in, const int* in_sizes, int n_in,
                              void* d_out, int out_size, void* d_ws, size_t ws_size,
                              hipStream_t stream) {
    const int* xt      = (const int*)d_in[0];
    const float* W1    = (const float*)d_in[1];
    // d_in[2] = b1 (cancels in BN), d_in[6] = b2 (cancels in BN)
    const float* g1    = (const float*)d_in[3];
    const float* beta1 = (const float*)d_in[4];
    const float* W2    = (const float*)d_in[5];
    const float* g2    = (const float*)d_in[7];
    const float* beta2 = (const float*)d_in[8];
    float* out = (float*)d_out;

    char* ws = (char*)d_ws;
    int*   cnt  = (int*)  (ws + OFF_CNT);
    float* a1   = (float*)(ws + OFF_A1);
    float* m1   = (float*)(ws + OFF_M1);
    float* a2   = (float*)(ws + OFF_A2);
    float* m2   = (float*)(ws + OFF_M2);
    float* ps1b = (float*)(ws + OFF_PS1B);
    float* ps2b = (float*)(ws + OFF_PS2B);
    unsigned short* W2b  = (unsigned short*)(ws + OFF_W2B);
    unsigned short* Hact = (unsigned short*)(ws + OFF_HACT);
    float* hpart = (float*)(ws + OFF_H2);
    float* h2 = hpart;   // chunk 0 doubles as the final h2

    // split-K factor chosen deterministically from ws_size (graph-safe)
    const int S = (ws_size >= OFF_H2 + 2 * PART_BYTES) ? 2 : 1;

    k_hist1b<<<1, 1024, 0, stream>>>(xt, cnt);
    k_stats1<<<1088, 256, 0, stream>>>(W1, cnt, g1, a1, m1);
    k_buildw2<<<4352, 256, 0, stream>>>(W1, a1, m1, beta1, Hact, W2, W2b);
    k_gemm<<<256 * S, 512, 0, stream>>>(Hact, W2b, hpart, INTER / S);
    k_reduce<<<512, 256, 0, stream>>>(hpart, cnt, h2, ps1b, ps2b, S);
    k_stats2f<<<128, 256, 0, stream>>>(ps1b, ps2b, g2, a2, m2);
    k_final<<<4096, 256, 0, stream>>>(h2, xt, a2, m2, beta2, out);
}